// Round 18
// baseline (182.606 us; speedup 1.0000x reference)
//
#include <hip/hip_runtime.h>
#include <hip/hip_bf16.h>
#include <math.h>

#define Hh 48
#define Ww 160
#define NP 7680      // H*W

using bf16 = __hip_bfloat16;
typedef __attribute__((ext_vector_type(8))) short v8s;
typedef __attribute__((ext_vector_type(4))) float v4f;

__device__ __forceinline__ float bfdec(unsigned short u) {
  return __uint_as_float(((unsigned)u) << 16);
}
__device__ __forceinline__ unsigned short bfenc(float x) {
  bf16 b = __float2bfloat16(x);
  return *(unsigned short*)&b;
}
__device__ __forceinline__ v8s ldv8(const unsigned short* p) {
  return *(const v8s*)p;
}
__device__ __forceinline__ float ldany(const void* p, size_t i, int isbf) {
  return isbf ? bfdec(((const unsigned short*)p)[i]) : ((const float*)p)[i];
}

__device__ __forceinline__ int mapidx(int i, int n, int mode) {
  if (mode == 0) return i < 0 ? 0 : (i >= n ? n - 1 : i);       // edge
  return i < 0 ? -i : (i >= n ? 2 * n - 2 - i : i);             // reflect
}

__device__ __forceinline__ float eluf(float v) { return v > 0.f ? v : expm1f(v); }
__device__ __forceinline__ float geluf(float v) {
  float c = v + 0.044715f * v * v * v;
  return 0.5f * v * (1.f + tanhf(0.7978845608028654f * c));
}

// depth-sort key, pure function of disp + invK row 2 (precomputed into zbuf;
// all comparisons read the same zbuf -> self-consistent ordering).
__device__ __forceinline__ float zkey(float d, float lin) {
  float scaled = fmaf(9.99f, d, 0.01f);
  float depth = fminf(fmaxf(1.f / scaled, 0.1f), 100.f);
  return lin * depth;
}

// in-block dtype sniff (L2-hot 4KB, same for every block)
__device__ __forceinline__ int sniff_local(const unsigned short* w, int* cnt) {
  int c = 0;
  for (int i = threadIdx.x; i < 2048; i += 256) {
    float a = fabsf(bfdec(w[i]));
    if (a > 1e-3f && a < 0.5f) c++;
  }
  cnt[threadIdx.x] = c;
  __syncthreads();
  for (int s = 128; s > 0; s >>= 1) {
    if (threadIdx.x < s) cnt[threadIdx.x] += cnt[threadIdx.x + s];
    __syncthreads();
  }
  int f = (cnt[0] > 1536) ? 1 : 0;
  __syncthreads();
  return f;
}

// ---------------- 16-px halo-LDS conv core, 6-deep A-load ILP ----------------
// 16-px strip (16 | 160: never wraps rows). Stage the 3x18 px halo in LDS
// ONCE (one barrier). K-loop runs in chunks of 6: preload 6 independent
// A-fragments into registers (forces 6-deep global-load ILP regardless of
// allocator heuristics -- R17 showed VGPR=20 serialized the A-stream), then
// 6x {LDS B-read + MFMA}. Waves >= NW skip the K-loop (dead-co slices).
template<int NCH, int PADR, int K, int PM, int NW>
__device__ __forceinline__ void halo_conv16(const unsigned short* __restrict__ A,
    const unsigned short* __restrict__ X, unsigned short* hx,
    int pxB, int coB, int tid, v4f& acc) {
  const int row0 = pxB / Ww, c0px = pxB - row0 * Ww;
  constexpr int CH8 = NCH / 8;
  for (int idx = tid; idx < 54 * CH8; idx += 256) {
    int e = idx / CH8, ch = (idx - e * CH8) * 8;
    int r = e / 18, j = e - r * 18;
    int gr = mapidx(row0 + r - 1, Hh, PM);
    int gc = mapidx(c0px + j - 1, Ww, PM);
    *(v8s*)&hx[(size_t)e * PADR + ch] = ldv8(&X[((size_t)gr * Ww + gc) * NCH + ch]);
  }
  __syncthreads();
  const int lane = tid & 63, wv = tid >> 6;
  const int m16 = lane & 15, quad = lane >> 4;
  acc = (v4f){0.f, 0.f, 0.f, 0.f};
  if (wv >= NW) return;
  const unsigned short* arow = &A[(size_t)(coB + wv * 16 + m16) * K + quad * 8];
  constexpr int NIT = K / 32;   // 36 or 18, both divisible by 6
  constexpr int CHK = 6;
#pragma unroll
  for (int c0 = 0; c0 < NIT; c0 += CHK) {
    v8s afs[CHK];
#pragma unroll
    for (int j = 0; j < CHK; j++) afs[j] = ldv8(&arow[(c0 + j) * 32]);
#pragma unroll
    for (int j = 0; j < CHK; j++) {
      const int kk = (c0 + j) * 32;
      const int t = kk / NCH, within = kk - t * NCH;
      const int r = t / 3, s = t - r * 3;
      v8s b0 = ldv8(&hx[(size_t)(r * 18 + m16 + s) * PADR + within + quad * 8]);
      acc = __builtin_amdgcn_mfma_f32_16x16x32_bf16(afs[j], b0, acc, 0, 0, 0);
    }
  }
}

// ---------------- merged sniff + transpose + prep (small LDS) ----------------
// blocks [0,960): LDS-tiled transpose x [128][NP] -> xb bf16 [NP][128]
// blocks [960,2434): weight permute / small-tensor load; dispf branch also
//   writes zbuf[i] = zkey(disp[i]) for the sort slices.
__global__ __launch_bounds__(256) void prep_all_k(int* __restrict__ flag,
    const void* __restrict__ xsrc, unsigned short* __restrict__ xb,
    const void* disp, const void* invK, const void* K, const void* rw2,
    const void* rb2, const void* sw2, const void* sb2, const void* ow2, const void* ob2,
    const void* rb1, const void* sb1, const void* ob1, const void* fb1, const void* fb2,
    const void* frb, const void* rot_w1, const void* scl_w1, const void* opa_w1,
    const void* fl_w1, const void* fl_w2, const void* fr_w,
    float* __restrict__ dispf, float* __restrict__ smallf, float* __restrict__ biasf,
    unsigned short* __restrict__ a_h1, unsigned short* __restrict__ a_fl1,
    unsigned short* __restrict__ a_fl2, unsigned short* __restrict__ a_fr,
    float* __restrict__ zbuf) {
  __shared__ float tile[32][33];
  __shared__ int cnt[256];
  const int f = sniff_local((const unsigned short*)fl_w1, cnt);
  if (blockIdx.x == 0 && threadIdx.x == 0) flag[0] = f;
  if (blockIdx.x < 960) {
    const int bx = blockIdx.x;
    const int pb = (bx % 240) * 32, cb = (bx / 240) * 32;
#pragma unroll
    for (int pass = 0; pass < 4; pass++) {
      int ci = (threadIdx.x >> 5) + pass * 8, pl = threadIdx.x & 31;
      tile[ci][pl] = ldany(xsrc, (size_t)(cb + ci) * NP + pb + pl, f);
    }
    __syncthreads();
#pragma unroll
    for (int pass = 0; pass < 4; pass++) {
      int pl = (threadIdx.x >> 5) + pass * 8, ci = threadIdx.x & 31;
      xb[(size_t)(pb + pl) * 128 + cb + ci] = bfenc(tile[ci][pl]);
    }
    return;
  }
  int i = (blockIdx.x - 960) * 256 + threadIdx.x;
  if (i < 7680) {
    float d = ldany(disp, i, f);
    dispf[i] = d;
    int gy = i / Ww, gx = i - gy * Ww;
    float M20 = ldany(invK, 8, f), M21 = ldany(invK, 9, f),
          M22 = ldany(invK, 10, f);
    zbuf[i] = zkey(d, fmaf(M20, (float)gx, fmaf(M21, (float)gy, M22)));
    return;
  }
  i -= 7680;
  if (i < 508) {
    const void* src; int off;
    if (i < 16)       { src = invK; off = i; }
    else if (i < 32)  { src = K;    off = i - 16; }
    else if (i < 320) { src = rw2;  off = i - 32; }
    else if (i < 324) { src = rb2;  off = i - 320; }
    else if (i < 486) { src = sw2;  off = i - 324; }
    else if (i < 489) { src = sb2;  off = i - 486; }
    else if (i < 507) { src = ow2;  off = i - 489; }
    else              { src = ob2;  off = i - 507; }
    smallf[i] = ldany(src, off, f); return;
  }
  i -= 508;
  if (i < 336) {
    if (i < 8) biasf[i] = ldany(rb1, i, f);
    else if (i < 14) biasf[i] = ldany(sb1, i - 8, f);
    else if (i < 16) biasf[i] = ldany(ob1, i - 14, f);
    else if (i < 144) biasf[i] = ldany(fb1, i - 16, f);
    else if (i < 208) biasf[i] = ldany(fb2, i - 144, f);
    else biasf[i] = ldany(frb, i - 208, f);
    return;
  }
  i -= 336;
  if (i < 73728) {   // a_h1 permuted (C=128)
    int co = i / 1152, rem = i - co * 1152;
    int t = rem >> 7, ci = rem & 127;
    float v = 0.f;
    if (co < 8) v = ldany(rot_w1, (size_t)co * 1152 + ci * 9 + t, f);
    else if (co < 14) v = ldany(scl_w1, (size_t)(co - 8) * 1152 + ci * 9 + t, f);
    else if (co < 16) v = ldany(opa_w1, (size_t)(co - 14) * 1152 + ci * 9 + t, f);
    a_h1[i] = bfenc(v); return;
  }
  i -= 73728;
  if (i < 147456) {
    int co = i / 1152, rem = i - co * 1152;
    int t = rem >> 7, ci = rem & 127;
    a_fl1[i] = bfenc(ldany(fl_w1, (size_t)co * 1152 + ci * 9 + t, f)); return;
  }
  i -= 147456;
  if (i < 73728) {
    int co = i / 1152, rem = i - co * 1152;
    int t = rem >> 7, ci = rem & 127;
    a_fl2[i] = bfenc(ldany(fl_w2, (size_t)co * 1152 + ci * 9 + t, f)); return;
  }
  i -= 73728;
  if (i < 73728) {   // a_fr permuted (C=64)
    int co = i / 576, rem = i - co * 576;
    int t = rem >> 6, ci = rem & 63;
    a_fr[i] = bfenc(ldany(fr_w, (size_t)co * 576 + ci * 9 + t, f));
    return;
  }
}

// ---------------- final fr conv: 16-px halo tiles ----------------
// grid (480, 2): pxB = bx*16, coB = by*64.
__global__ __launch_bounds__(256, 4) void gemm_conv32_k(const unsigned short* __restrict__ A,
    const unsigned short* __restrict__ X, const float* __restrict__ bias,
    void* __restrict__ out, const int* __restrict__ flag) {
  __shared__ __align__(16) unsigned short hx[54 * 72];   // 7.8 KB
  const int tid = threadIdx.x;
  const int pxB = blockIdx.x * 16;
  const int coB = blockIdx.y * 64;
  v4f acc;
  halo_conv16<64, 72, 576, 1, 4>(A, X, hx, pxB, coB, tid, acc);
  const int lane = tid & 63, wv = tid >> 6;
  const int m16 = lane & 15, quad = lane >> 4;
  const int obf = *flag;
#pragma unroll
  for (int r = 0; r < 4; r++) {
    int co = coB + wv * 16 + quad * 4 + r;
    int px = pxB + m16;
    float v = eluf(acc[r] + bias[co]);
    size_t oi = (size_t)co * NP + px;
    if (obf) ((unsigned short*)out)[oi] = bfenc(v);
    else ((float*)out)[oi] = v;
  }
}

// ---------------- fused fl1 + head conv + depth-sort (16-px tiles) ----------------
// grid (480, 5): y in {0,1}: fl1 conv (co 0-63 / 64-127, 16 px); y==2: head1
// conv (16 px, NW=1 -- only wave 0 computes the 16 valid co); y in {3,4}:
// counting sort -- 960 units x 8 gaussians x 32 segs, 60 float4/thread from
// L2-hot zbuf. LDS: conv 14.7 KB / sort 1 KB -> ~10 blocks/CU.
__global__ __launch_bounds__(256, 4) void conv_fused1_k(
    const unsigned short* __restrict__ a_fl1, const unsigned short* __restrict__ a_h1,
    const unsigned short* __restrict__ X, const float* __restrict__ biasf,
    const float* __restrict__ zbuf, unsigned short* __restrict__ t1b,
    float* __restrict__ h1, int* __restrict__ ord) {
  __shared__ __align__(16) unsigned char smem[14688];
  const int tid = threadIdx.x;
  const int zy = blockIdx.y;
  if (zy >= 3) {
    int (*part)[32] = (int (*)[32])smem;        // 1 KB
    const int unit = (zy - 3) * 480 + blockIdx.x;   // 0..959
    const int g = tid >> 5;        // local gaussian 0..7
    const int seg = tid & 31;      // segment 0..31
    const int i = unit * 8 + g;
    const float zi = zbuf[i];
    const float4* zv = (const float4*)(zbuf + seg * 240);
    int c = 0;
    for (int t = 0; t < 60; t++) {
      float4 z4 = zv[t];
      int jb = seg * 240 + t * 4;
      c += (z4.x < zi || (z4.x == zi && jb + 0 < i)) ? 1 : 0;
      c += (z4.y < zi || (z4.y == zi && jb + 1 < i)) ? 1 : 0;
      c += (z4.z < zi || (z4.z == zi && jb + 2 < i)) ? 1 : 0;
      c += (z4.w < zi || (z4.w == zi && jb + 3 < i)) ? 1 : 0;
    }
    part[g][seg] = c;
    __syncthreads();
    if (seg == 0) {
      int s = 0;
#pragma unroll
      for (int q = 0; q < 32; q++) s += part[g][q];
      ord[s] = i;
    }
    return;
  }
  unsigned short* hx = (unsigned short*)smem;   // 54*136 halves = 14.7 KB
  const bool ishead = (zy == 2);
  const int pxB = blockIdx.x * 16;
  const int coB = ishead ? 0 : zy * 64;
  const unsigned short* A = ishead ? a_h1 : a_fl1;
  v4f acc;
  if (ishead) halo_conv16<128, 136, 1152, 0, 1>(A, X, hx, pxB, coB, tid, acc);
  else        halo_conv16<128, 136, 1152, 1, 4>(A, X, hx, pxB, coB, tid, acc);
  const int lane = tid & 63, wv = tid >> 6;
  const int m16 = lane & 15, quad = lane >> 4;
  if (ishead) {
    if (wv == 0) {
#pragma unroll
      for (int r = 0; r < 4; r++) {
        int co = quad * 4 + r;
        int px = pxB + m16;
        h1[(size_t)co * NP + px] = geluf(acc[r] + biasf[co]);
      }
    }
  } else {
    const int cb = coB + wv * 16 + quad * 4;
    int px = pxB + m16;
    ushort4 o;
    o.x = bfenc(eluf(acc[0] + biasf[16 + cb + 0]));
    o.y = bfenc(eluf(acc[1] + biasf[16 + cb + 1]));
    o.z = bfenc(eluf(acc[2] + biasf[16 + cb + 2]));
    o.w = bfenc(eluf(acc[3] + biasf[16 + cb + 3]));
    *(ushort4*)&t1b[(size_t)px * 128 + cb] = o;
  }
}

// ---------------- merged fl2 GEMM + head2/per-gaussian prep ----------------
// blocks [0,480): fl2 conv (16-px halo tiles, K=1152, reflect, px-major t1b
// -> t2eb bf16 [c][NP]). blocks [480,510): head2 + gaussian prep.
__global__ __launch_bounds__(256, 4) void fl2_head2_k(
    const unsigned short* __restrict__ a_fl2, const unsigned short* __restrict__ t1b,
    const float* __restrict__ biasf, unsigned short* __restrict__ t2eb,
    const float* __restrict__ h1, const float* __restrict__ smallf,
    const float* __restrict__ dispf, float* __restrict__ params) {
  __shared__ __align__(16) unsigned short hx[54 * 136];   // 14.7 KB
  const int tid = threadIdx.x;
  if (blockIdx.x < 480) {
    const int pxB = blockIdx.x * 16;
    v4f acc;
    halo_conv16<128, 136, 1152, 1, 4>(a_fl2, t1b, hx, pxB, 0, tid, acc);
    const int lane = tid & 63, wv = tid >> 6;
    const int m16 = lane & 15, quad = lane >> 4;
#pragma unroll
    for (int r = 0; r < 4; r++) {
      int co = wv * 16 + quad * 4 + r;
      int px = pxB + m16;
      t2eb[(size_t)co * NP + px] = bfenc(eluf(acc[r] + biasf[144 + co]));
    }
    return;
  }
  // ---- head2 + prep path ----
  const float* invK = smallf;
  const float* Km   = smallf + 16;
  const float* rw2  = smallf + 32;
  const float* rb2  = smallf + 320;
  const float* sw2  = smallf + 324;
  const float* sb2  = smallf + 486;
  const float* ow2  = smallf + 489;
  const float* ob2  = smallf + 507;
  int p = (blockIdx.x - 480) * 256 + tid;
  if (p >= NP) return;
  int hh = p / Ww, ww = p - hh * Ww;
  float racc[4], sacc[3], oacc;
#pragma unroll
  for (int i = 0; i < 4; i++) racc[i] = rb2[i];
#pragma unroll
  for (int i = 0; i < 3; i++) sacc[i] = sb2[i];
  oacc = ob2[0];
  for (int ci = 0; ci < 16; ci++) {
    float t9[9];
#pragma unroll
    for (int r = 0; r < 3; r++) {
      int rr = mapidx(hh + r - 1, Hh, 0);
#pragma unroll
      for (int s = 0; s < 3; s++) {
        int cc = mapidx(ww + s - 1, Ww, 0);
        t9[r * 3 + s] = h1[(size_t)ci * NP + rr * Ww + cc];
      }
    }
    if (ci < 8) {
      for (int co = 0; co < 4; co++)
#pragma unroll
        for (int k = 0; k < 9; k++)
          racc[co] = fmaf(t9[k], rw2[(co * 8 + ci) * 9 + k], racc[co]);
    } else if (ci < 14) {
      int c2 = ci - 8;
      for (int co = 0; co < 3; co++)
#pragma unroll
        for (int k = 0; k < 9; k++)
          sacc[co] = fmaf(t9[k], sw2[(co * 6 + c2) * 9 + k], sacc[co]);
    } else {
      int c2 = ci - 14;
#pragma unroll
      for (int k = 0; k < 9; k++)
        oacc = fmaf(t9[k], ow2[c2 * 9 + k], oacc);
    }
  }
  float nq = sqrtf(racc[0]*racc[0] + racc[1]*racc[1] + racc[2]*racc[2] + racc[3]*racc[3]);
  nq = fmaxf(nq, 1e-12f);
  float qw = racc[0] / nq, qx = racc[1] / nq, qy = racc[2] / nq, qz = racc[3] / nq;
  float s0 = fabsf(sacc[0]), s1 = fabsf(sacc[1]), s2 = fabsf(sacc[2]);
  float opa = 1.f / (1.f + __expf(-oacc));
  float d = dispf[p];
  float scaled = 0.01f + 9.99f * d;
  float depth = fminf(fmaxf(1.f / scaled, 0.1f), 100.f);
  float M00 = invK[0], M01 = invK[1], M02 = invK[2];
  float M10 = invK[4], M11 = invK[5], M12 = invK[6];
  float M20 = invK[8], M21 = invK[9], M22 = invK[10];
  float gxf = (float)ww, gyf = (float)hh;
  float X = (M00 * gxf + M01 * gyf + M02) * depth;
  float Y = (M10 * gxf + M11 * gyf + M12) * depth;
  float Z = (M20 * gxf + M21 * gyf + M22) * depth;
  float fxk = Km[0], fyk = Km[5];
  float cxk = Km[2], cyk = Km[6];
  float u = fxk * X / Z + cxk;
  float v = fyk * Y / Z + cyk;
  float R00 = 1.f - 2.f*(qy*qy + qz*qz), R01 = 2.f*(qx*qy - qw*qz), R02 = 2.f*(qx*qz + qw*qy);
  float R10 = 2.f*(qx*qy + qw*qz), R11 = 1.f - 2.f*(qx*qx + qz*qz), R12 = 2.f*(qy*qz - qw*qx);
  float R20 = 2.f*(qx*qz - qw*qy), R21 = 2.f*(qy*qz + qw*qx), R22 = 1.f - 2.f*(qx*qx + qy*qy);
  float M0a = R00*s0, M0b = R01*s1, M0c = R02*s2;
  float M1a = R10*s0, M1b = R11*s1, M1c = R12*s2;
  float M2a = R20*s0, M2b = R21*s1, M2c = R22*s2;
  float S00 = M0a*M0a + M0b*M0b + M0c*M0c;
  float S01 = M0a*M1a + M0b*M1b + M0c*M1c;
  float S02 = M0a*M2a + M0b*M2b + M0c*M2c;
  float S11 = M1a*M1a + M1b*M1b + M1c*M1c;
  float S12 = M1a*M2a + M1b*M2b + M1c*M2c;
  float S22 = M2a*M2a + M2b*M2b + M2c*M2c;
  float iz = 1.f / Z;
  float j00 = fxk * iz, j02 = -fxk * X * iz * iz;
  float j11 = fyk * iz, j12 = -fyk * Y * iz * iz;
  float c00 = j00*j00*S00 + 2.f*j00*j02*S02 + j02*j02*S22 + 0.3f;
  float c01 = j00*j11*S01 + j00*j12*S02 + j02*j11*S12 + j02*j12*S22;
  float c11 = j11*j11*S11 + 2.f*j11*j12*S12 + j12*j12*S22 + 0.3f;
  float det = c00 * c11 - c01 * c01;
  float idet = 1.f / det;
  float* pr = params + (size_t)p * 8;
  pr[0] = u; pr[1] = v; pr[2] = c11 * idet; pr[3] = -c01 * idet;
  pr[4] = c00 * idet; pr[5] = opa; pr[6] = Z; pr[7] = 0.f;
}

// ---------------- depth-sequential MFMA raster, fused on-the-fly gather ----------------
__global__ __launch_bounds__(64) void raster_seq_k(const int* __restrict__ ord,
    const float* __restrict__ params, const unsigned short* __restrict__ t2eb,
    unsigned short* __restrict__ levb) {
  __shared__ unsigned int Wl[64][17];
  __shared__ int ords[32];
  const int lane = threadIdx.x;
  const int m16 = lane & 15, quad = lane >> 4;
  const int pxB = blockIdx.x * 64;
  const int mypx = pxB + lane;
  const float px = (float)(mypx % Ww), py = (float)(mypx / Ww);
  float T = 1.f;
  v4f acc[4][4];
#pragma unroll
  for (int a = 0; a < 4; a++)
#pragma unroll
    for (int b = 0; b < 4; b++) acc[a][b] = (v4f){0.f, 0.f, 0.f, 0.f};
  for (int sub = 0; sub < NP / 32; sub++) {
    const int g0 = sub * 32;
    if (lane < 32) ords[lane] = ord[g0 + lane];
    __syncthreads();
    int myord[8];
#pragma unroll
    for (int j = 0; j < 8; j++) myord[j] = ords[quad * 8 + j];
    float al[32];
#pragma unroll
    for (int j = 0; j < 32; j++) {
      const float* pp = params + ((size_t)ords[j] << 3);
      float4 pa = *(const float4*)pp;
      float4 pb = *(const float4*)(pp + 4);
      float dx = px - pa.x, dy = py - pa.y;
      float power = -0.5f * (pa.z * dx * dx + pb.x * dy * dy) - pa.w * dx * dy;
      al[j] = fminf(pb.y * __expf(power), 0.99f);
    }
#pragma unroll
    for (int jj = 0; jj < 16; jj++) {
      float w0 = al[2 * jj] * T;     T *= 1.f - al[2 * jj];
      float w1 = al[2 * jj + 1] * T; T *= 1.f - al[2 * jj + 1];
      Wl[lane][jj] = (unsigned)bfenc(w0) | ((unsigned)bfenc(w1) << 16);
    }
    v8s af[4], bfr[4];
#pragma unroll
    for (int a = 0; a < 4; a++) {
      unsigned d0 = Wl[a * 16 + m16][quad * 4 + 0];
      unsigned d1 = Wl[a * 16 + m16][quad * 4 + 1];
      unsigned d2 = Wl[a * 16 + m16][quad * 4 + 2];
      unsigned d3 = Wl[a * 16 + m16][quad * 4 + 3];
      v8s t;
      t[0] = (short)(d0 & 0xffff); t[1] = (short)(d0 >> 16);
      t[2] = (short)(d1 & 0xffff); t[3] = (short)(d1 >> 16);
      t[4] = (short)(d2 & 0xffff); t[5] = (short)(d2 >> 16);
      t[6] = (short)(d3 & 0xffff); t[7] = (short)(d3 >> 16);
      af[a] = t;
    }
#pragma unroll
    for (int b = 0; b < 4; b++) {
      const unsigned short* fp = &t2eb[(size_t)(b * 16 + m16) * NP];
      v8s t;
#pragma unroll
      for (int j = 0; j < 8; j++) t[j] = (short)fp[myord[j]];
      bfr[b] = t;
    }
#pragma unroll
    for (int a = 0; a < 4; a++)
#pragma unroll
      for (int b = 0; b < 4; b++)
        acc[a][b] = __builtin_amdgcn_mfma_f32_16x16x32_bf16(af[a], bfr[b], acc[a][b], 0, 0, 0);
    if (__all(T < 1e-7f)) break;
    __syncthreads();
  }
#pragma unroll
  for (int a = 0; a < 4; a++) {
#pragma unroll
    for (int b = 0; b < 4; b++) {
#pragma unroll
      for (int r = 0; r < 4; r++) {
        levb[(size_t)(pxB + a * 16 + quad * 4 + r) * 64 + b * 16 + m16] =
            bfenc(acc[a][b][r]);
      }
    }
  }
}

extern "C" void kernel_launch(void* const* d_in, const int* in_sizes, int n_in,
                              void* d_out, int out_size, void* d_ws, size_t ws_size,
                              hipStream_t stream) {
  (void)in_sizes; (void)n_in; (void)out_size; (void)ws_size;
  const void* init_feature = d_in[0];
  const void* disp   = d_in[1];
  const void* invK   = d_in[2];
  const void* Km     = d_in[3];
  const void* rot_w1 = d_in[4];
  const void* rot_b1 = d_in[5];
  const void* rot_w2 = d_in[6];
  const void* rot_b2 = d_in[7];
  const void* scl_w1 = d_in[8];
  const void* scl_b1 = d_in[9];
  const void* scl_w2 = d_in[10];
  const void* scl_b2 = d_in[11];
  const void* opa_w1 = d_in[12];
  const void* opa_b1 = d_in[13];
  const void* opa_w2 = d_in[14];
  const void* opa_b2 = d_in[15];
  const void* fl_w1  = d_in[16];
  const void* fl_b1  = d_in[17];
  const void* fl_w2  = d_in[18];
  const void* fl_b2  = d_in[19];
  const void* fr_w   = d_in[20];
  const void* fr_b   = d_in[21];

  float* wsf = (float*)d_ws;
  int*   flag    = (int*)wsf;                   // @0        16
  float* smallf  = wsf + 16;                    // 512
  float* dispf   = wsf + 528;                   // 7680
  float* biasf   = wsf + 8208;                  // 512
  unsigned short* a_h1  = (unsigned short*)(wsf + 8720);    // 36864 f
  unsigned short* a_fl1 = (unsigned short*)(wsf + 45584);   // 73728 f
  unsigned short* a_fl2 = (unsigned short*)(wsf + 119312);  // 36864 f
  unsigned short* a_fr  = (unsigned short*)(wsf + 156176);  // 36864 f
  unsigned short* xb    = (unsigned short*)(wsf + 193040);  // 491520 f
  unsigned short* t1b   = (unsigned short*)(wsf + 684560);  // 491520 f ([px][128])
  unsigned short* t2eb  = (unsigned short*)(wsf + 1176080); // bf16 [c][NP]
  float* h1      = wsf + 1667600;               // 122880
  float* params  = wsf + 1790480;               // 61440
  unsigned short* levb = (unsigned short*)(wsf + 2896400);  // 245760 f
  float* zbuf    = wsf + 3142160;               // 7680
  int*   ord     = (int*)(wsf + 3157520);       // 7680

  prep_all_k<<<2434, 256, 0, stream>>>(flag, init_feature, xb,
      disp, invK, Km, rot_w2, rot_b2, scl_w2, scl_b2, opa_w2, opa_b2,
      rot_b1, scl_b1, opa_b1, fl_b1, fl_b2, fr_b,
      rot_w1, scl_w1, opa_w1, fl_w1, fl_w2, fr_w,
      dispf, smallf, biasf, a_h1, a_fl1, a_fl2, a_fr, zbuf);

  conv_fused1_k<<<dim3(480, 5), 256, 0, stream>>>(a_fl1, a_h1, xb, biasf,
                                                  zbuf, t1b, h1, ord);
  fl2_head2_k<<<510, 256, 0, stream>>>(a_fl2, t1b, biasf, t2eb, h1, smallf,
                                       dispf, params);
  raster_seq_k<<<120, 64, 0, stream>>>(ord, params, t2eb, levb);
  gemm_conv32_k<<<dim3(480, 2), 256, 0, stream>>>(
      a_fr, levb, biasf + 208, d_out, flag);
}

// Round 19
// 179.174 us; speedup vs baseline: 1.0192x; 1.0192x over previous
//
#include <hip/hip_runtime.h>
#include <hip/hip_bf16.h>
#include <math.h>

#define Hh 48
#define Ww 160
#define NP 7680      // H*W

using bf16 = __hip_bfloat16;
typedef __attribute__((ext_vector_type(8))) short v8s;
typedef __attribute__((ext_vector_type(4))) float v4f;

__device__ __forceinline__ float bfdec(unsigned short u) {
  return __uint_as_float(((unsigned)u) << 16);
}
__device__ __forceinline__ unsigned short bfenc(float x) {
  bf16 b = __float2bfloat16(x);
  return *(unsigned short*)&b;
}
__device__ __forceinline__ v8s ldv8(const unsigned short* p) {
  return *(const v8s*)p;
}
__device__ __forceinline__ float ldany(const void* p, size_t i, int isbf) {
  return isbf ? bfdec(((const unsigned short*)p)[i]) : ((const float*)p)[i];
}

__device__ __forceinline__ int mapidx(int i, int n, int mode) {
  if (mode == 0) return i < 0 ? 0 : (i >= n ? n - 1 : i);       // edge
  return i < 0 ? -i : (i >= n ? 2 * n - 2 - i : i);             // reflect
}

__device__ __forceinline__ float eluf(float v) { return v > 0.f ? v : expm1f(v); }
__device__ __forceinline__ float geluf(float v) {
  float c = v + 0.044715f * v * v * v;
  return 0.5f * v * (1.f + tanhf(0.7978845608028654f * c));
}

// depth-sort key, pure function of disp + invK row 2 (precomputed into zbuf;
// all comparisons read the same zbuf -> self-consistent ordering).
__device__ __forceinline__ float zkey(float d, float lin) {
  float scaled = fmaf(9.99f, d, 0.01f);
  float depth = fminf(fmaxf(1.f / scaled, 0.1f), 100.f);
  return lin * depth;
}

// in-block dtype sniff (L2-hot 4KB, same for every block)
__device__ __forceinline__ int sniff_local(const unsigned short* w, int* cnt) {
  int c = 0;
  for (int i = threadIdx.x; i < 2048; i += 256) {
    float a = fabsf(bfdec(w[i]));
    if (a > 1e-3f && a < 0.5f) c++;
  }
  cnt[threadIdx.x] = c;
  __syncthreads();
  for (int s = 128; s > 0; s >>= 1) {
    if (threadIdx.x < s) cnt[threadIdx.x] += cnt[threadIdx.x + s];
    __syncthreads();
  }
  int f = (cnt[0] > 1536) ? 1 : 0;
  __syncthreads();
  return f;
}

// ---------------- 16-px halo-LDS conv core, forced 6-deep A-load MLP ----------------
// 16-px strip (16 | 160: never wraps rows). Stage the 3x18 px halo in LDS
// ONCE (one barrier). K-loop in chunks of 6: issue 6 independent A-loads,
// then a keep-alive asm barrier pins all 6 values live (forces the compiler
// to issue all loads before the first MFMA -- R17/R18 showed it otherwise
// folds to load->use pairs at VGPR=16, serializing ~36 cold L2/L3 misses),
// then 6x {LDS B-read + MFMA}. Waves >= NW skip the K-loop.
template<int NCH, int PADR, int K, int PM, int NW>
__device__ __forceinline__ void halo_conv16(const unsigned short* __restrict__ A,
    const unsigned short* __restrict__ X, unsigned short* hx,
    int pxB, int coB, int tid, v4f& acc) {
  const int row0 = pxB / Ww, c0px = pxB - row0 * Ww;
  constexpr int CH8 = NCH / 8;
  for (int idx = tid; idx < 54 * CH8; idx += 256) {
    int e = idx / CH8, ch = (idx - e * CH8) * 8;
    int r = e / 18, j = e - r * 18;
    int gr = mapidx(row0 + r - 1, Hh, PM);
    int gc = mapidx(c0px + j - 1, Ww, PM);
    *(v8s*)&hx[(size_t)e * PADR + ch] = ldv8(&X[((size_t)gr * Ww + gc) * NCH + ch]);
  }
  __syncthreads();
  const int lane = tid & 63, wv = tid >> 6;
  const int m16 = lane & 15, quad = lane >> 4;
  acc = (v4f){0.f, 0.f, 0.f, 0.f};
  if (wv >= NW) return;
  const unsigned short* arow = &A[(size_t)(coB + wv * 16 + m16) * K + quad * 8];
  constexpr int NIT = K / 32;   // 36 or 18, both divisible by 6
  constexpr int CHK = 6;
#pragma unroll
  for (int c0 = 0; c0 < NIT; c0 += CHK) {
    v8s afs[CHK];
#pragma unroll
    for (int j = 0; j < CHK; j++) afs[j] = ldv8(&arow[(c0 + j) * 32]);
    // keep-alive: all 6 loads must be materialized here -> 6-deep MLP
    asm volatile("" :: "v"(afs[0]), "v"(afs[1]), "v"(afs[2]),
                       "v"(afs[3]), "v"(afs[4]), "v"(afs[5]));
#pragma unroll
    for (int j = 0; j < CHK; j++) {
      const int kk = (c0 + j) * 32;
      const int t = kk / NCH, within = kk - t * NCH;
      const int r = t / 3, s = t - r * 3;
      v8s b0 = ldv8(&hx[(size_t)(r * 18 + m16 + s) * PADR + within + quad * 8]);
      acc = __builtin_amdgcn_mfma_f32_16x16x32_bf16(afs[j], b0, acc, 0, 0, 0);
    }
  }
}

// ---------------- merged sniff + transpose + prep (small LDS) ----------------
// blocks [0,960): LDS-tiled transpose x [128][NP] -> xb bf16 [NP][128]
// blocks [960,2434): weight permute / small-tensor load; dispf branch also
//   writes zbuf[i] = zkey(disp[i]) for the sort slices.
__global__ __launch_bounds__(256) void prep_all_k(int* __restrict__ flag,
    const void* __restrict__ xsrc, unsigned short* __restrict__ xb,
    const void* disp, const void* invK, const void* K, const void* rw2,
    const void* rb2, const void* sw2, const void* sb2, const void* ow2, const void* ob2,
    const void* rb1, const void* sb1, const void* ob1, const void* fb1, const void* fb2,
    const void* frb, const void* rot_w1, const void* scl_w1, const void* opa_w1,
    const void* fl_w1, const void* fl_w2, const void* fr_w,
    float* __restrict__ dispf, float* __restrict__ smallf, float* __restrict__ biasf,
    unsigned short* __restrict__ a_h1, unsigned short* __restrict__ a_fl1,
    unsigned short* __restrict__ a_fl2, unsigned short* __restrict__ a_fr,
    float* __restrict__ zbuf) {
  __shared__ float tile[32][33];
  __shared__ int cnt[256];
  const int f = sniff_local((const unsigned short*)fl_w1, cnt);
  if (blockIdx.x == 0 && threadIdx.x == 0) flag[0] = f;
  if (blockIdx.x < 960) {
    const int bx = blockIdx.x;
    const int pb = (bx % 240) * 32, cb = (bx / 240) * 32;
#pragma unroll
    for (int pass = 0; pass < 4; pass++) {
      int ci = (threadIdx.x >> 5) + pass * 8, pl = threadIdx.x & 31;
      tile[ci][pl] = ldany(xsrc, (size_t)(cb + ci) * NP + pb + pl, f);
    }
    __syncthreads();
#pragma unroll
    for (int pass = 0; pass < 4; pass++) {
      int pl = (threadIdx.x >> 5) + pass * 8, ci = threadIdx.x & 31;
      xb[(size_t)(pb + pl) * 128 + cb + ci] = bfenc(tile[ci][pl]);
    }
    return;
  }
  int i = (blockIdx.x - 960) * 256 + threadIdx.x;
  if (i < 7680) {
    float d = ldany(disp, i, f);
    dispf[i] = d;
    int gy = i / Ww, gx = i - gy * Ww;
    float M20 = ldany(invK, 8, f), M21 = ldany(invK, 9, f),
          M22 = ldany(invK, 10, f);
    zbuf[i] = zkey(d, fmaf(M20, (float)gx, fmaf(M21, (float)gy, M22)));
    return;
  }
  i -= 7680;
  if (i < 508) {
    const void* src; int off;
    if (i < 16)       { src = invK; off = i; }
    else if (i < 32)  { src = K;    off = i - 16; }
    else if (i < 320) { src = rw2;  off = i - 32; }
    else if (i < 324) { src = rb2;  off = i - 320; }
    else if (i < 486) { src = sw2;  off = i - 324; }
    else if (i < 489) { src = sb2;  off = i - 486; }
    else if (i < 507) { src = ow2;  off = i - 489; }
    else              { src = ob2;  off = i - 507; }
    smallf[i] = ldany(src, off, f); return;
  }
  i -= 508;
  if (i < 336) {
    if (i < 8) biasf[i] = ldany(rb1, i, f);
    else if (i < 14) biasf[i] = ldany(sb1, i - 8, f);
    else if (i < 16) biasf[i] = ldany(ob1, i - 14, f);
    else if (i < 144) biasf[i] = ldany(fb1, i - 16, f);
    else if (i < 208) biasf[i] = ldany(fb2, i - 144, f);
    else biasf[i] = ldany(frb, i - 208, f);
    return;
  }
  i -= 336;
  if (i < 73728) {   // a_h1 permuted (C=128)
    int co = i / 1152, rem = i - co * 1152;
    int t = rem >> 7, ci = rem & 127;
    float v = 0.f;
    if (co < 8) v = ldany(rot_w1, (size_t)co * 1152 + ci * 9 + t, f);
    else if (co < 14) v = ldany(scl_w1, (size_t)(co - 8) * 1152 + ci * 9 + t, f);
    else if (co < 16) v = ldany(opa_w1, (size_t)(co - 14) * 1152 + ci * 9 + t, f);
    a_h1[i] = bfenc(v); return;
  }
  i -= 73728;
  if (i < 147456) {
    int co = i / 1152, rem = i - co * 1152;
    int t = rem >> 7, ci = rem & 127;
    a_fl1[i] = bfenc(ldany(fl_w1, (size_t)co * 1152 + ci * 9 + t, f)); return;
  }
  i -= 147456;
  if (i < 73728) {
    int co = i / 1152, rem = i - co * 1152;
    int t = rem >> 7, ci = rem & 127;
    a_fl2[i] = bfenc(ldany(fl_w2, (size_t)co * 1152 + ci * 9 + t, f)); return;
  }
  i -= 73728;
  if (i < 73728) {   // a_fr permuted (C=64)
    int co = i / 576, rem = i - co * 576;
    int t = rem >> 6, ci = rem & 63;
    a_fr[i] = bfenc(ldany(fr_w, (size_t)co * 576 + ci * 9 + t, f));
    return;
  }
}

// ---------------- final fr conv: 16-px halo tiles ----------------
// grid (480, 2): pxB = bx*16, coB = by*64.
__global__ __launch_bounds__(256, 4) void gemm_conv32_k(const unsigned short* __restrict__ A,
    const unsigned short* __restrict__ X, const float* __restrict__ bias,
    void* __restrict__ out, const int* __restrict__ flag) {
  __shared__ __align__(16) unsigned short hx[54 * 72];   // 7.8 KB
  const int tid = threadIdx.x;
  const int pxB = blockIdx.x * 16;
  const int coB = blockIdx.y * 64;
  v4f acc;
  halo_conv16<64, 72, 576, 1, 4>(A, X, hx, pxB, coB, tid, acc);
  const int lane = tid & 63, wv = tid >> 6;
  const int m16 = lane & 15, quad = lane >> 4;
  const int obf = *flag;
#pragma unroll
  for (int r = 0; r < 4; r++) {
    int co = coB + wv * 16 + quad * 4 + r;
    int px = pxB + m16;
    float v = eluf(acc[r] + bias[co]);
    size_t oi = (size_t)co * NP + px;
    if (obf) ((unsigned short*)out)[oi] = bfenc(v);
    else ((float*)out)[oi] = v;
  }
}

// ---------------- fused fl1 + head conv + depth-sort (16-px tiles) ----------------
// grid (480, 5): y in {0,1}: fl1 conv (co 0-63 / 64-127, 16 px); y==2: head1
// conv (16 px, NW=1 -- only wave 0 computes the 16 valid co); y in {3,4}:
// counting sort -- 960 units x 8 gaussians x 32 segs, 60 float4/thread from
// L2-hot zbuf. LDS: conv 14.7 KB / sort 1 KB -> ~10 blocks/CU.
__global__ __launch_bounds__(256, 4) void conv_fused1_k(
    const unsigned short* __restrict__ a_fl1, const unsigned short* __restrict__ a_h1,
    const unsigned short* __restrict__ X, const float* __restrict__ biasf,
    const float* __restrict__ zbuf, unsigned short* __restrict__ t1b,
    float* __restrict__ h1, int* __restrict__ ord) {
  __shared__ __align__(16) unsigned char smem[14688];
  const int tid = threadIdx.x;
  const int zy = blockIdx.y;
  if (zy >= 3) {
    int (*part)[32] = (int (*)[32])smem;        // 1 KB
    const int unit = (zy - 3) * 480 + blockIdx.x;   // 0..959
    const int g = tid >> 5;        // local gaussian 0..7
    const int seg = tid & 31;      // segment 0..31
    const int i = unit * 8 + g;
    const float zi = zbuf[i];
    const float4* zv = (const float4*)(zbuf + seg * 240);
    int c = 0;
    for (int t = 0; t < 60; t++) {
      float4 z4 = zv[t];
      int jb = seg * 240 + t * 4;
      c += (z4.x < zi || (z4.x == zi && jb + 0 < i)) ? 1 : 0;
      c += (z4.y < zi || (z4.y == zi && jb + 1 < i)) ? 1 : 0;
      c += (z4.z < zi || (z4.z == zi && jb + 2 < i)) ? 1 : 0;
      c += (z4.w < zi || (z4.w == zi && jb + 3 < i)) ? 1 : 0;
    }
    part[g][seg] = c;
    __syncthreads();
    if (seg == 0) {
      int s = 0;
#pragma unroll
      for (int q = 0; q < 32; q++) s += part[g][q];
      ord[s] = i;
    }
    return;
  }
  unsigned short* hx = (unsigned short*)smem;   // 54*136 halves = 14.7 KB
  const bool ishead = (zy == 2);
  const int pxB = blockIdx.x * 16;
  const int coB = ishead ? 0 : zy * 64;
  const unsigned short* A = ishead ? a_h1 : a_fl1;
  v4f acc;
  if (ishead) halo_conv16<128, 136, 1152, 0, 1>(A, X, hx, pxB, coB, tid, acc);
  else        halo_conv16<128, 136, 1152, 1, 4>(A, X, hx, pxB, coB, tid, acc);
  const int lane = tid & 63, wv = tid >> 6;
  const int m16 = lane & 15, quad = lane >> 4;
  if (ishead) {
    if (wv == 0) {
#pragma unroll
      for (int r = 0; r < 4; r++) {
        int co = quad * 4 + r;
        int px = pxB + m16;
        h1[(size_t)co * NP + px] = geluf(acc[r] + biasf[co]);
      }
    }
  } else {
    const int cb = coB + wv * 16 + quad * 4;
    int px = pxB + m16;
    ushort4 o;
    o.x = bfenc(eluf(acc[0] + biasf[16 + cb + 0]));
    o.y = bfenc(eluf(acc[1] + biasf[16 + cb + 1]));
    o.z = bfenc(eluf(acc[2] + biasf[16 + cb + 2]));
    o.w = bfenc(eluf(acc[3] + biasf[16 + cb + 3]));
    *(ushort4*)&t1b[(size_t)px * 128 + cb] = o;
  }
}

// ---------------- merged fl2 GEMM + head2/per-gaussian prep ----------------
// blocks [0,480): fl2 conv (16-px halo tiles, K=1152, reflect, px-major t1b
// -> t2eb bf16 [c][NP]). blocks [480,510): head2 + gaussian prep.
__global__ __launch_bounds__(256, 4) void fl2_head2_k(
    const unsigned short* __restrict__ a_fl2, const unsigned short* __restrict__ t1b,
    const float* __restrict__ biasf, unsigned short* __restrict__ t2eb,
    const float* __restrict__ h1, const float* __restrict__ smallf,
    const float* __restrict__ dispf, float* __restrict__ params) {
  __shared__ __align__(16) unsigned short hx[54 * 136];   // 14.7 KB
  const int tid = threadIdx.x;
  if (blockIdx.x < 480) {
    const int pxB = blockIdx.x * 16;
    v4f acc;
    halo_conv16<128, 136, 1152, 1, 4>(a_fl2, t1b, hx, pxB, 0, tid, acc);
    const int lane = tid & 63, wv = tid >> 6;
    const int m16 = lane & 15, quad = lane >> 4;
#pragma unroll
    for (int r = 0; r < 4; r++) {
      int co = wv * 16 + quad * 4 + r;
      int px = pxB + m16;
      t2eb[(size_t)co * NP + px] = bfenc(eluf(acc[r] + biasf[144 + co]));
    }
    return;
  }
  // ---- head2 + prep path ----
  const float* invK = smallf;
  const float* Km   = smallf + 16;
  const float* rw2  = smallf + 32;
  const float* rb2  = smallf + 320;
  const float* sw2  = smallf + 324;
  const float* sb2  = smallf + 486;
  const float* ow2  = smallf + 489;
  const float* ob2  = smallf + 507;
  int p = (blockIdx.x - 480) * 256 + tid;
  if (p >= NP) return;
  int hh = p / Ww, ww = p - hh * Ww;
  float racc[4], sacc[3], oacc;
#pragma unroll
  for (int i = 0; i < 4; i++) racc[i] = rb2[i];
#pragma unroll
  for (int i = 0; i < 3; i++) sacc[i] = sb2[i];
  oacc = ob2[0];
  for (int ci = 0; ci < 16; ci++) {
    float t9[9];
#pragma unroll
    for (int r = 0; r < 3; r++) {
      int rr = mapidx(hh + r - 1, Hh, 0);
#pragma unroll
      for (int s = 0; s < 3; s++) {
        int cc = mapidx(ww + s - 1, Ww, 0);
        t9[r * 3 + s] = h1[(size_t)ci * NP + rr * Ww + cc];
      }
    }
    if (ci < 8) {
      for (int co = 0; co < 4; co++)
#pragma unroll
        for (int k = 0; k < 9; k++)
          racc[co] = fmaf(t9[k], rw2[(co * 8 + ci) * 9 + k], racc[co]);
    } else if (ci < 14) {
      int c2 = ci - 8;
      for (int co = 0; co < 3; co++)
#pragma unroll
        for (int k = 0; k < 9; k++)
          sacc[co] = fmaf(t9[k], sw2[(co * 6 + c2) * 9 + k], sacc[co]);
    } else {
      int c2 = ci - 14;
#pragma unroll
      for (int k = 0; k < 9; k++)
        oacc = fmaf(t9[k], ow2[c2 * 9 + k], oacc);
    }
  }
  float nq = sqrtf(racc[0]*racc[0] + racc[1]*racc[1] + racc[2]*racc[2] + racc[3]*racc[3]);
  nq = fmaxf(nq, 1e-12f);
  float qw = racc[0] / nq, qx = racc[1] / nq, qy = racc[2] / nq, qz = racc[3] / nq;
  float s0 = fabsf(sacc[0]), s1 = fabsf(sacc[1]), s2 = fabsf(sacc[2]);
  float opa = 1.f / (1.f + __expf(-oacc));
  float d = dispf[p];
  float scaled = 0.01f + 9.99f * d;
  float depth = fminf(fmaxf(1.f / scaled, 0.1f), 100.f);
  float M00 = invK[0], M01 = invK[1], M02 = invK[2];
  float M10 = invK[4], M11 = invK[5], M12 = invK[6];
  float M20 = invK[8], M21 = invK[9], M22 = invK[10];
  float gxf = (float)ww, gyf = (float)hh;
  float X = (M00 * gxf + M01 * gyf + M02) * depth;
  float Y = (M10 * gxf + M11 * gyf + M12) * depth;
  float Z = (M20 * gxf + M21 * gyf + M22) * depth;
  float fxk = Km[0], fyk = Km[5];
  float cxk = Km[2], cyk = Km[6];
  float u = fxk * X / Z + cxk;
  float v = fyk * Y / Z + cyk;
  float R00 = 1.f - 2.f*(qy*qy + qz*qz), R01 = 2.f*(qx*qy - qw*qz), R02 = 2.f*(qx*qz + qw*qy);
  float R10 = 2.f*(qx*qy + qw*qz), R11 = 1.f - 2.f*(qx*qx + qz*qz), R12 = 2.f*(qy*qz - qw*qx);
  float R20 = 2.f*(qx*qz - qw*qy), R21 = 2.f*(qy*qz + qw*qx), R22 = 1.f - 2.f*(qx*qx + qy*qy);
  float M0a = R00*s0, M0b = R01*s1, M0c = R02*s2;
  float M1a = R10*s0, M1b = R11*s1, M1c = R12*s2;
  float M2a = R20*s0, M2b = R21*s1, M2c = R22*s2;
  float S00 = M0a*M0a + M0b*M0b + M0c*M0c;
  float S01 = M0a*M1a + M0b*M1b + M0c*M1c;
  float S02 = M0a*M2a + M0b*M2b + M0c*M2c;
  float S11 = M1a*M1a + M1b*M1b + M1c*M1c;
  float S12 = M1a*M2a + M1b*M2b + M1c*M2c;
  float S22 = M2a*M2a + M2b*M2b + M2c*M2c;
  float iz = 1.f / Z;
  float j00 = fxk * iz, j02 = -fxk * X * iz * iz;
  float j11 = fyk * iz, j12 = -fyk * Y * iz * iz;
  float c00 = j00*j00*S00 + 2.f*j00*j02*S02 + j02*j02*S22 + 0.3f;
  float c01 = j00*j11*S01 + j00*j12*S02 + j02*j11*S12 + j02*j12*S22;
  float c11 = j11*j11*S11 + 2.f*j11*j12*S12 + j12*j12*S22 + 0.3f;
  float det = c00 * c11 - c01 * c01;
  float idet = 1.f / det;
  float* pr = params + (size_t)p * 8;
  pr[0] = u; pr[1] = v; pr[2] = c11 * idet; pr[3] = -c01 * idet;
  pr[4] = c00 * idet; pr[5] = opa; pr[6] = Z; pr[7] = 0.f;
}

// ---------------- depth-sequential MFMA raster, fused on-the-fly gather ----------------
__global__ __launch_bounds__(64) void raster_seq_k(const int* __restrict__ ord,
    const float* __restrict__ params, const unsigned short* __restrict__ t2eb,
    unsigned short* __restrict__ levb) {
  __shared__ unsigned int Wl[64][17];
  __shared__ int ords[32];
  const int lane = threadIdx.x;
  const int m16 = lane & 15, quad = lane >> 4;
  const int pxB = blockIdx.x * 64;
  const int mypx = pxB + lane;
  const float px = (float)(mypx % Ww), py = (float)(mypx / Ww);
  float T = 1.f;
  v4f acc[4][4];
#pragma unroll
  for (int a = 0; a < 4; a++)
#pragma unroll
    for (int b = 0; b < 4; b++) acc[a][b] = (v4f){0.f, 0.f, 0.f, 0.f};
  for (int sub = 0; sub < NP / 32; sub++) {
    const int g0 = sub * 32;
    if (lane < 32) ords[lane] = ord[g0 + lane];
    __syncthreads();
    int myord[8];
#pragma unroll
    for (int j = 0; j < 8; j++) myord[j] = ords[quad * 8 + j];
    float al[32];
#pragma unroll
    for (int j = 0; j < 32; j++) {
      const float* pp = params + ((size_t)ords[j] << 3);
      float4 pa = *(const float4*)pp;
      float4 pb = *(const float4*)(pp + 4);
      float dx = px - pa.x, dy = py - pa.y;
      float power = -0.5f * (pa.z * dx * dx + pb.x * dy * dy) - pa.w * dx * dy;
      al[j] = fminf(pb.y * __expf(power), 0.99f);
    }
#pragma unroll
    for (int jj = 0; jj < 16; jj++) {
      float w0 = al[2 * jj] * T;     T *= 1.f - al[2 * jj];
      float w1 = al[2 * jj + 1] * T; T *= 1.f - al[2 * jj + 1];
      Wl[lane][jj] = (unsigned)bfenc(w0) | ((unsigned)bfenc(w1) << 16);
    }
    v8s af[4], bfr[4];
#pragma unroll
    for (int a = 0; a < 4; a++) {
      unsigned d0 = Wl[a * 16 + m16][quad * 4 + 0];
      unsigned d1 = Wl[a * 16 + m16][quad * 4 + 1];
      unsigned d2 = Wl[a * 16 + m16][quad * 4 + 2];
      unsigned d3 = Wl[a * 16 + m16][quad * 4 + 3];
      v8s t;
      t[0] = (short)(d0 & 0xffff); t[1] = (short)(d0 >> 16);
      t[2] = (short)(d1 & 0xffff); t[3] = (short)(d1 >> 16);
      t[4] = (short)(d2 & 0xffff); t[5] = (short)(d2 >> 16);
      t[6] = (short)(d3 & 0xffff); t[7] = (short)(d3 >> 16);
      af[a] = t;
    }
#pragma unroll
    for (int b = 0; b < 4; b++) {
      const unsigned short* fp = &t2eb[(size_t)(b * 16 + m16) * NP];
      v8s t;
#pragma unroll
      for (int j = 0; j < 8; j++) t[j] = (short)fp[myord[j]];
      bfr[b] = t;
    }
#pragma unroll
    for (int a = 0; a < 4; a++)
#pragma unroll
      for (int b = 0; b < 4; b++)
        acc[a][b] = __builtin_amdgcn_mfma_f32_16x16x32_bf16(af[a], bfr[b], acc[a][b], 0, 0, 0);
    if (__all(T < 1e-7f)) break;
    __syncthreads();
  }
#pragma unroll
  for (int a = 0; a < 4; a++) {
#pragma unroll
    for (int b = 0; b < 4; b++) {
#pragma unroll
      for (int r = 0; r < 4; r++) {
        levb[(size_t)(pxB + a * 16 + quad * 4 + r) * 64 + b * 16 + m16] =
            bfenc(acc[a][b][r]);
      }
    }
  }
}

extern "C" void kernel_launch(void* const* d_in, const int* in_sizes, int n_in,
                              void* d_out, int out_size, void* d_ws, size_t ws_size,
                              hipStream_t stream) {
  (void)in_sizes; (void)n_in; (void)out_size; (void)ws_size;
  const void* init_feature = d_in[0];
  const void* disp   = d_in[1];
  const void* invK   = d_in[2];
  const void* Km     = d_in[3];
  const void* rot_w1 = d_in[4];
  const void* rot_b1 = d_in[5];
  const void* rot_w2 = d_in[6];
  const void* rot_b2 = d_in[7];
  const void* scl_w1 = d_in[8];
  const void* scl_b1 = d_in[9];
  const void* scl_w2 = d_in[10];
  const void* scl_b2 = d_in[11];
  const void* opa_w1 = d_in[12];
  const void* opa_b1 = d_in[13];
  const void* opa_w2 = d_in[14];
  const void* opa_b2 = d_in[15];
  const void* fl_w1  = d_in[16];
  const void* fl_b1  = d_in[17];
  const void* fl_w2  = d_in[18];
  const void* fl_b2  = d_in[19];
  const void* fr_w   = d_in[20];
  const void* fr_b   = d_in[21];

  float* wsf = (float*)d_ws;
  int*   flag    = (int*)wsf;                   // @0        16
  float* smallf  = wsf + 16;                    // 512
  float* dispf   = wsf + 528;                   // 7680
  float* biasf   = wsf + 8208;                  // 512
  unsigned short* a_h1  = (unsigned short*)(wsf + 8720);    // 36864 f
  unsigned short* a_fl1 = (unsigned short*)(wsf + 45584);   // 73728 f
  unsigned short* a_fl2 = (unsigned short*)(wsf + 119312);  // 36864 f
  unsigned short* a_fr  = (unsigned short*)(wsf + 156176);  // 36864 f
  unsigned short* xb    = (unsigned short*)(wsf + 193040);  // 491520 f
  unsigned short* t1b   = (unsigned short*)(wsf + 684560);  // 491520 f ([px][128])
  unsigned short* t2eb  = (unsigned short*)(wsf + 1176080); // bf16 [c][NP]
  float* h1      = wsf + 1667600;               // 122880
  float* params  = wsf + 1790480;               // 61440
  unsigned short* levb = (unsigned short*)(wsf + 2896400);  // 245760 f
  float* zbuf    = wsf + 3142160;               // 7680
  int*   ord     = (int*)(wsf + 3157520);       // 7680

  prep_all_k<<<2434, 256, 0, stream>>>(flag, init_feature, xb,
      disp, invK, Km, rot_w2, rot_b2, scl_w2, scl_b2, opa_w2, opa_b2,
      rot_b1, scl_b1, opa_b1, fl_b1, fl_b2, fr_b,
      rot_w1, scl_w1, opa_w1, fl_w1, fl_w2, fr_w,
      dispf, smallf, biasf, a_h1, a_fl1, a_fl2, a_fr, zbuf);

  conv_fused1_k<<<dim3(480, 5), 256, 0, stream>>>(a_fl1, a_h1, xb, biasf,
                                                  zbuf, t1b, h1, ord);
  fl2_head2_k<<<510, 256, 0, stream>>>(a_fl2, t1b, biasf, t2eb, h1, smallf,
                                       dispf, params);
  raster_seq_k<<<120, 64, 0, stream>>>(ord, params, t2eb, levb);
  gemm_conv32_k<<<dim3(480, 2), 256, 0, stream>>>(
      a_fr, levb, biasf + 208, d_out, flag);
}